// Round 16
// baseline (188.772 us; speedup 1.0000x reference)
//
#include <hip/hip_runtime.h>
#include <hip/hip_bf16.h>
#include <math.h>

// ---------------------------------------------------------------------------
// MAMIL round 16: conv at 128 threads (2 waves/image), VGPR<=128.
//  R15's conv held bfr[3][11]+av[11] ~200 VGPR -> 2 waves/SIMD, fully
//  latency-bound (one wave's dependent-chain wall time). Now: av[11] cached
//  per mt, bfr[11] reloaded per (mt,nt) as clustered L1-hot burst (VMEM pipe
//  idle; same values/order -> bit-identical), launch_bounds(128,4) ->
//  16 waves/CU = 2x latency hiding, per-wave work halved.
// GEMM/tail identical to R15 (136.5us, absmax 3.9e-3).
// ---------------------------------------------------------------------------

typedef short short8 __attribute__((ext_vector_type(8)));
typedef float f32x4  __attribute__((ext_vector_type(4)));

__device__ inline short f2bf(float f) {
    unsigned u = __builtin_bit_cast(unsigned, f);
    u += 0x7fff + ((u >> 16) & 1);
    return (short)(u >> 16);
}
__device__ inline float bf2f(short h) {
    unsigned u = ((unsigned)(unsigned short)h) << 16;
    return __builtin_bit_cast(float, u);
}
__device__ inline f32x4 mfma16(short8 a, short8 b, f32x4 c) {
    return __builtin_amdgcn_mfma_f32_16x16x32_bf16(a, b, c, 0, 0, 0);
}

// ---------------- fused weight prep + workspace zeroing (hi only) ----------------
__global__ __launch_bounds__(256) void prep_all_kernel(
    const float* __restrict__ fc1w, short* __restrict__ fc1whi,
    const float* __restrict__ fc2w, short* __restrict__ fc2whi,
    const float* __restrict__ nbrw, short* __restrict__ nbrwhi,
    const float* __restrict__ prw,  short* __restrict__ prwhi,
    const float* __restrict__ w1,   short* __restrict__ w1m,
    const float* __restrict__ w2,   short* __restrict__ w2mp,
    float* __restrict__ St, float* __restrict__ embs)
{
    const int b = blockIdx.x, tid = threadIdx.x;
    if (b < 3456) {
        int i = b*256 + tid; if (i < 884736) fc1whi[i] = f2bf(fc1w[i]);
    } else if (b < 4480) {
        int i = (b-3456)*256 + tid; if (i < 262144) fc2whi[i] = f2bf(fc2w[i]);
    } else if (b < 5504) {
        int i = (b-4480)*256 + tid; if (i < 262144) nbrwhi[i] = f2bf(nbrw[i]);
    } else if (b < 9600) {
        int i = (b-5504)*256 + tid; if (i < 1048576) prwhi[i] = f2bf(prw[i]);
    } else if (b < 9606) {
        int i = (b-9600)*256 + tid;
        if (i < 1536) {
            int c = i >> 5, k = i & 31;
            w1m[i] = (c < 36 && k < 16) ? f2bf(w1[c*16 + k]) : (short)0;
        }
    } else if (b < 9672) {
        // w2mp [48][352]: ks0-8 = tap=ks, ic=j (j<32); ks9 = tap=j>>2,
        // ic=32+(j&3); ks10 = (j<4) tap8 ic32+j else 0.
        int i = (b-9606)*256 + tid;
        if (i < 16896) {
            int oc = i / 352, r = i % 352, ks = r >> 5, j = r & 31;
            float v = 0.0f;
            if (ks < 9)          v = w2[oc*324 + j*9 + ks];
            else if (ks == 9)    v = w2[oc*324 + (32 + (j & 3))*9 + (j >> 2)];
            else if (j < 4)      v = w2[oc*324 + (32 + j)*9 + 8];
            w2mp[i] = f2bf(v);
        }
    } else if (b < 9752) {
        int i = (b-9672)*256 + tid; if (i < 20480) St[i] = 0.0f;
    } else {
        int i = (b-9752)*256 + tid; if (i < 10240) embs[i] = 0.0f;
    }
}

// ---------------- fused conv1+pool -> conv2+pool (2 waves = 1 image) ----------------
__global__ __launch_bounds__(128, 4) void conv_mfma_kernel(
    const float* __restrict__ x,     // [2048][1024]
    const short* __restrict__ w1m,   // [48][32]
    const float* __restrict__ b1,    // [36]
    const short* __restrict__ w2mp,  // [48][352] K-packed
    const float* __restrict__ b2,    // [48]
    short* __restrict__ Hfhi)        // [2048][1728], oc*36+r2
{
    __shared__ __align__(16) short sxb[2][1024];     // bf16(x) + shift-left-1 copy
    __shared__ __align__(16) short sh1[196*40];      // 80B rows (72B data)
    const int n = blockIdx.x, tid = threadIdx.x;
    const int w = tid >> 6, l = tid & 63;
    const int g = l >> 4, fr = l & 15;

    // stage x: 2 float4 chunks per thread -> dual-parity bf16 copies
    #pragma unroll
    for (int i = 0; i < 2; ++i) {
        const float4 v4 = ((const float4*)(x + (size_t)n*1024))[tid + 128*i];
        short v[4] = { f2bf(v4.x), f2bf(v4.y), f2bf(v4.z), f2bf(v4.w) };
        const int c4 = (tid + 128*i)*4;
        *(short4*)&sxb[0][c4] = *(short4*)v;
        if (c4 & 31) sxb[1][c4-1] = v[0];
        sxb[1][c4+0] = v[1];
        sxb[1][c4+1] = v[2];
        sxb[1][c4+2] = v[3];
    }
    short8 bw1[3];
    #pragma unroll
    for (int nt = 0; nt < 3; ++nt)
        bw1[nt] = *(const short8*)(w1m + (nt*16 + fr)*32 + g*8);
    __syncthreads();

    // ---- conv1 (1->36, 4x4, 32->29) + relu + 2x2 pool -> sh1 [196][36] ----
    for (int mt = w; mt < 49; mt += 2) {
        const int pp = mt*16 + fr;
        const int q = pp >> 2, dd = pp & 3;
        const int iy0 = 2*(q/14) + (dd >> 1), ix0 = 2*(q%14) + (dd & 1);
        short8 af = {};
        if (g < 2) {
            const int par = ix0 & 1;
            const int colp = ix0 - par;
            const unsigned* p0 = (const unsigned*)&sxb[par][(iy0 + 2*g)*32 + colp];
            union { unsigned u[4]; short8 s; } uu;
            uu.u[0] = p0[0];  uu.u[1] = p0[1];
            uu.u[2] = p0[16]; uu.u[3] = p0[17];
            af = uu.s;
        }
        f32x4 acc[3] = {};
        #pragma unroll
        for (int nt = 0; nt < 3; ++nt) acc[nt] = mfma16(af, bw1[nt], acc[nt]);
        const int q1 = mt*4 + g;          // pooled pos 0..195
        #pragma unroll
        for (int nt = 0; nt < 3; ++nt) {
            const int c = nt*16 + fr;
            if (c < 36) {
                float m = fmaxf(fmaxf(acc[nt][0], acc[nt][1]),
                                fmaxf(acc[nt][2], acc[nt][3]));
                m = fmaxf(m + b1[c], 0.0f);
                *(short*)((char*)sh1 + (q1*80 + c*2)) = f2bf(m);
            }
        }
    }
    __syncthreads();   // sh1 complete (cross-wave)

    // ---- conv2: mt split across waves; av cached per mt; bfr per (mt,nt)
    //      as clustered L1-hot bursts ----
    for (int mt = w; mt < 9; mt += 2) {
        const int pp = mt*16 + fr;
        const int q2 = pp >> 2, dd = pp & 3;
        const int oy = 2*(q2/6) + (dd >> 1), ox = 2*(q2%6) + (dd & 1);
        short8 av[11];
        #pragma unroll
        for (int tap = 0; tap < 9; ++tap) {
            const int hr = (oy + tap/3)*14 + ox + tap%3;
            av[tap] = *(const short8*)((char*)sh1 + (hr*80 + g*16));
        }
        {   // ks9: taps g*2, g*2+1, ic 32..35 each
            const int t0 = g*2, t1 = g*2 + 1;
            const int h0 = (oy + t0/3)*14 + ox + t0%3;
            const int h1 = (oy + t1/3)*14 + ox + t1%3;
            union { short4 h[2]; short8 s; } u9;
            u9.h[0] = *(const short4*)((char*)sh1 + (h0*80 + 64));
            u9.h[1] = *(const short4*)((char*)sh1 + (h1*80 + 64));
            av[9] = u9.s;
        }
        {   // ks10: g==0 lanes carry tap8 ic32..35
            short8 a10 = {};
            if (g == 0) {
                const int h8 = (oy + 2)*14 + ox + 2;
                *(short4*)&a10 = *(const short4*)((char*)sh1 + (h8*80 + 64));
            }
            av[10] = a10;
        }
        #pragma unroll
        for (int nt = 0; nt < 3; ++nt) {
            short8 bfr[11];
            {
                const short* wb = w2mp + (size_t)(nt*16 + fr)*352 + g*8;
                #pragma unroll
                for (int ks = 0; ks < 11; ++ks)
                    bfr[ks] = *(const short8*)(wb + ks*32);
            }
            f32x4 acc = {};
            #pragma unroll
            for (int ks = 0; ks < 11; ++ks)
                acc = mfma16(av[ks], bfr[ks], acc);
            const int oc = nt*16 + fr;
            float m = fmaxf(fmaxf(acc[0], acc[1]), fmaxf(acc[2], acc[3]));
            m = fmaxf(m + b2[oc], 0.0f);
            Hfhi[(size_t)n*1728 + oc*36 + (mt*4 + g)] = f2bf(m);
        }
    }
}

// ---------------- MFMA GEMM: C = act(A_hi @ W_hi^T + bias) ----------------
// 512 threads, double-buffered LDS, ONE barrier per K-step.
template<int ACT, int OUTF32, int OUTBF, int TSC>
__global__ __launch_bounds__(512, 2) void gemm_kernel(
    const short* __restrict__ Ahi, const short* __restrict__ Whi,
    const float* __restrict__ bias,
    float* __restrict__ Cf, short* __restrict__ Chi,
    const float* __restrict__ Tm, float* __restrict__ St,
    const int N, const int K)
{
    __shared__ __align__(16) short sA[2][4096];   // [buf][row*64+k], swz ((row&7)<<4)
    __shared__ __align__(16) short sB[2][4096];
    const int bn = blockIdx.x, bm = blockIdx.y;
    const int tid = threadIdx.x, l = tid & 63, w = tid >> 6, g = l >> 4, fr = l & 15;
    const int wm = w & 3, wn = w >> 2;
    const int srow = tid >> 3;              // 0..63
    const int wbyte = srow*128 + (tid & 7)*16;
    const int swb = (srow & 7) << 4;
    const size_t aoff = (size_t)(bm*64 + srow)*K + (tid & 7)*8;
    const size_t boff = (size_t)(bn*64 + srow)*K + (tid & 7)*8;
    f32x4 acc[2] = {};
    short8 ra = *(const short8*)(Ahi + aoff);
    short8 rb = *(const short8*)(Whi + boff);
    int cur = 0;
    for (int k0 = 0; k0 < K; k0 += 64) {
        *(short8*)((char*)&sA[cur][0] + (wbyte ^ swb)) = ra;
        *(short8*)((char*)&sB[cur][0] + (wbyte ^ swb)) = rb;
        __syncthreads();
        if (k0 + 64 < K) {
            ra = *(const short8*)(Ahi + aoff + k0 + 64);
            rb = *(const short8*)(Whi + boff + k0 + 64);
        }
        const int ar = wm*16 + fr, asw = (ar & 7) << 4;
        const short8 ah0 = *(const short8*)((char*)&sA[cur][0] + ((ar*128      + g*16) ^ asw));
        const short8 ah1 = *(const short8*)((char*)&sA[cur][0] + ((ar*128 + 64 + g*16) ^ asw));
        #pragma unroll
        for (int ntl = 0; ntl < 2; ++ntl) {
            const int br = (wn*2 + ntl)*16 + fr, bsw = (br & 7) << 4;
            const short8 bh0 = *(const short8*)((char*)&sB[cur][0] + ((br*128      + g*16) ^ bsw));
            const short8 bh1 = *(const short8*)((char*)&sB[cur][0] + ((br*128 + 64 + g*16) ^ bsw));
            acc[ntl] = mfma16(ah0, bh0, acc[ntl]);
            acc[ntl] = mfma16(ah1, bh1, acc[ntl]);
        }
        cur ^= 1;
    }
    float pv[2][4];
    #pragma unroll
    for (int ntl = 0; ntl < 2; ++ntl) {
        const int col = bn*64 + (wn*2 + ntl)*16 + fr;
        const float bv = bias[col];
        #pragma unroll
        for (int i = 0; i < 4; ++i) {
            const int row = bm*64 + wm*16 + g*4 + i;
            float v = acc[ntl][i] + bv;
            if (ACT == 1) v = fmaxf(v, 0.0f);
            if (ACT == 2) v = tanhf(v);
            pv[ntl][i] = v;
            const size_t idx = (size_t)row*N + col;
            if (OUTF32) Cf[idx] = v;
            if (OUTBF)  Chi[idx] = f2bf(v);
        }
    }
    if (TSC) {
        for (int t = 0; t < 10; ++t) {
            float tm[2];
            #pragma unroll
            for (int ntl = 0; ntl < 2; ++ntl)
                tm[ntl] = Tm[t*1024 + bn*64 + (wn*2 + ntl)*16 + fr];
            float part[4];
            #pragma unroll
            for (int i = 0; i < 4; ++i) {
                float s = 0.0f;
                #pragma unroll
                for (int ntl = 0; ntl < 2; ++ntl) s = fmaf(pv[ntl][i], tm[ntl], s);
                #pragma unroll
                for (int m = 1; m <= 8; m <<= 1) s += __shfl_xor(s, m);
                part[i] = s;
            }
            if (fr == 0) {
                #pragma unroll
                for (int i = 0; i < 4; ++i)
                    atomicAdd(&St[t*2048 + bm*64 + wm*16 + g*4 + i], part[i]);
            }
        }
    }
}

// ---------------- sparse neighborhood attention (ILP batched) ----------------
__global__ __launch_bounds__(64) void nbr_attn_kernel(
    const float* __restrict__ H, const float* __restrict__ An,
    short* __restrict__ H2hi)       // [2048][1024] bf16 hi only
{
    const int i = blockIdx.x;
    const int lane = threadIdx.x;
    const int r = i >> 6, c = i & 63;
    const int DR[8] = {-1,-1,-1, 0, 0, 1, 1, 1};
    const int DC[8] = {-1, 0, 1,-1, 1,-1, 0, 1};
    int nbr[8]; bool val[8];
    #pragma unroll
    for (int j = 0; j < 8; ++j) {
        const int rr = r + DR[j], cc = c + DC[j];
        val[j] = (rr >= 0 && rr < 32 && cc >= 0 && cc < 64);
        nbr[j] = val[j] ? rr*64 + cc : i;
    }
    float hi[8];
    #pragma unroll
    for (int q = 0; q < 8; ++q) hi[q] = H[(size_t)i*512 + q*64 + lane];
    float av[8][8];
    #pragma unroll
    for (int j = 0; j < 8; ++j) {
        const float* an = An + (size_t)nbr[j]*512 + lane;
        #pragma unroll
        for (int q = 0; q < 8; ++q) av[j][q] = an[q*64];
    }
    float lg[8];
    #pragma unroll
    for (int j = 0; j < 8; ++j) {
        float s = 0.0f;
        #pragma unroll
        for (int q = 0; q < 8; ++q) s = fmaf(hi[q], av[j][q], s);
        #pragma unroll
        for (int off = 32; off; off >>= 1) s += __shfl_xor(s, off);
        lg[j] = val[j] ? s : -1e30f;
    }
    float mx = -1e30f;
    #pragma unroll
    for (int j = 0; j < 8; ++j) mx = fmaxf(mx, lg[j]);
    float sum = 0.0f; float al[8];
    #pragma unroll
    for (int j = 0; j < 8; ++j) { al[j] = expf(lg[j]-mx); sum += al[j]; }
    const float inv = 1.0f/sum;
    #pragma unroll
    for (int j = 0; j < 8; ++j) {
        const float* hj = H + (size_t)nbr[j]*512 + lane;
        #pragma unroll
        for (int q = 0; q < 8; ++q) av[j][q] = hj[q*64];
    }
    float hn[8] = {};
    #pragma unroll
    for (int j = 0; j < 8; ++j) {
        const float a = al[j]*inv;
        #pragma unroll
        for (int q = 0; q < 8; ++q) hn[q] = fmaf(a, av[j][q], hn[q]);
    }
    #pragma unroll
    for (int q = 0; q < 8; ++q) {
        const size_t i0 = (size_t)i*1024 + q*64 + lane;
        H2hi[i0]       = f2bf(hi[q]);
        H2hi[i0 + 512] = f2bf(hn[q]);
    }
}

// ---------------- betas (from St) + embs partials; writes minv ----------------
__global__ __launch_bounds__(256) void beta_embs_kernel(
    const float* __restrict__ St,   // [10][2048]
    const short* __restrict__ H2hi, // [2048][1024] bf16
    float* __restrict__ embs,       // [10][1024] (zeroed)
    float* __restrict__ minv)       // [10][2] = {mx, inv}
{
    const int t = blockIdx.y;
    const int tid = threadIdx.x;
    __shared__ float red[256];
    __shared__ float sb[256];
    float mx = -1e30f;
    for (int n = tid; n < 2048; n += 256) mx = fmaxf(mx, St[t*2048+n]);
    red[tid] = mx; __syncthreads();
    for (int s = 128; s; s >>= 1) { if (tid < s) red[tid] = fmaxf(red[tid], red[tid+s]); __syncthreads(); }
    mx = red[0]; __syncthreads();
    float sum = 0.0f;
    for (int n = tid; n < 2048; n += 256) sum += expf(St[t*2048+n]-mx);
    red[tid] = sum; __syncthreads();
    for (int s = 128; s; s >>= 1) { if (tid < s) red[tid] += red[tid+s]; __syncthreads(); }
    const float inv = 1.0f/red[0];
    if (blockIdx.x == 0 && tid == 0) { minv[t*2+0] = mx; minv[t*2+1] = inv; }
    const int colc = blockIdx.x & 3;
    const int nc   = blockIdx.x >> 2;
    sb[tid] = expf(St[t*2048 + nc*256 + tid] - mx) * inv;
    __syncthreads();
    const int col = colc*256 + tid;
    float acc = 0.0f;
    for (int j = 0; j < 256; ++j)
        acc = fmaf(sb[j], bf2f(H2hi[(size_t)(nc*256+j)*1024 + col]), acc);
    atomicAdd(&embs[t*1024+col], acc);
}

// ---------------- gpart[t,k] = tanh(embs[t].gw1[k]+gb1[k])*gw2[k] ----------------
__global__ __launch_bounds__(64) void glob_g2_kernel(
    const float* __restrict__ embs, const float* __restrict__ gw1,
    const float* __restrict__ gb1, const float* __restrict__ gw2,
    float* __restrict__ gpart)      // [10][128]
{
    const int k = blockIdx.x, t = blockIdx.y, lane = threadIdx.x;
    const float* e  = embs + t*1024 + lane;
    const float* wv = gw1 + k*1024 + lane;
    float s = 0.0f;
    #pragma unroll
    for (int q = 0; q < 16; ++q) s = fmaf(e[q*64], wv[q*64], s);
    #pragma unroll
    for (int off = 32; off; off >>= 1) s += __shfl_xor(s, off);
    if (lane == 0) gpart[t*128 + k] = tanhf(s + gb1[k]) * gw2[k];
}

// ---------------- gamma softmax + M + A + classifier ----------------
__global__ __launch_bounds__(256) void final3_kernel(
    const float* __restrict__ gpart, const float* __restrict__ gb2,
    const float* __restrict__ embs,  const float* __restrict__ St,
    const float* __restrict__ minv,
    const float* __restrict__ cw, const float* __restrict__ cb,
    float* __restrict__ out)         // [2051] = Y_prob[2], Y_hat[1], A[2048]
{
    __shared__ float gam[10];
    __shared__ float sM[1024];
    __shared__ float red[256];
    __shared__ float gv[10];
    __shared__ float smx[10], sinv[10];
    __shared__ float v0s;
    const int tid = threadIdx.x;
    for (int t = 0; t < 10; ++t) {
        float s = (tid < 128) ? gpart[t*128 + tid] : 0.0f;
        red[tid] = s; __syncthreads();
        for (int st = 128; st; st >>= 1) { if (tid < st) red[tid] += red[tid+st]; __syncthreads(); }
        if (tid == 0) gv[t] = red[0];
        __syncthreads();
    }
    if (tid < 10) { smx[tid] = minv[tid*2]; sinv[tid] = minv[tid*2+1]; }
    if (tid == 0) {
        float mx = -1e30f;
        for (int t = 0; t < 10; ++t) mx = fmaxf(mx, gv[t] + gb2[0]);
        float sum = 0.0f;
        for (int t = 0; t < 10; ++t) { gam[t] = expf(gv[t] + gb2[0] - mx); sum += gam[t]; }
        for (int t = 0; t < 10; ++t) gam[t] /= sum;
    }
    __syncthreads();
    for (int col = tid; col < 1024; col += 256) {
        float m = 0.0f;
        for (int t = 0; t < 10; ++t) m = fmaf(gam[t], embs[t*1024+col], m);
        sM[col] = m;
    }
    for (int n = tid; n < 2048; n += 256) {
        float a = 0.0f;
        for (int t = 0; t < 10; ++t)
            a = fmaf(gam[t], expf(St[t*2048+n]-smx[t])*sinv[t], a);
        out[3+n] = a;
    }
    __syncthreads();
    float s0 = 0.0f, s1 = 0.0f;
    for (int q = tid; q < 1024; q += 256) {
        s0 = fmaf(sM[q], cw[q], s0);
        s1 = fmaf(sM[q], cw[1024+q], s1);
    }
    red[tid] = s0; __syncthreads();
    for (int s = 128; s; s >>= 1) { if (tid < s) red[tid] += red[tid+s]; __syncthreads(); }
    if (tid == 0) v0s = red[0];
    __syncthreads();
    red[tid] = s1; __syncthreads();
    for (int s = 128; s; s >>= 1) { if (tid < s) red[tid] += red[tid+s]; __syncthreads(); }
    if (tid == 0) {
        const float l0 = v0s + cb[0], l1 = red[0] + cb[1];
        const float p0 = 1.0f/(1.0f+expf(-l0));
        const float p1 = 1.0f/(1.0f+expf(-l1));
        out[0] = p0; out[1] = p1;
        out[2] = (p1 > p0) ? 1.0f : 0.0f;
    }
}

extern "C" void kernel_launch(void* const* d_in, const int* in_sizes, int n_in,
                              void* d_out, int out_size, void* d_ws, size_t ws_size,
                              hipStream_t stream)
{
    (void)in_sizes; (void)n_in; (void)out_size; (void)ws_size;
    const float* x        = (const float*)d_in[0];
    const float* conv1_w  = (const float*)d_in[2];
    const float* conv1_b  = (const float*)d_in[3];
    const float* conv2_w  = (const float*)d_in[4];
    const float* conv2_b  = (const float*)d_in[5];
    const float* fc1_w    = (const float*)d_in[6];
    const float* fc1_b    = (const float*)d_in[7];
    const float* fc2_w    = (const float*)d_in[8];
    const float* fc2_b    = (const float*)d_in[9];
    const float* nbr_w    = (const float*)d_in[10];
    const float* nbr_b    = (const float*)d_in[11];
    const float* templ    = (const float*)d_in[12];
    const float* proto_w  = (const float*)d_in[13];
    const float* proto_b  = (const float*)d_in[14];
    const float* glob_w1  = (const float*)d_in[15];
    const float* glob_b1  = (const float*)d_in[16];
    const float* glob_w2  = (const float*)d_in[17];
    const float* glob_b2  = (const float*)d_in[18];
    const float* cls_w    = (const float*)d_in[19];
    const float* cls_b    = (const float*)d_in[20];
    float* out = (float*)d_out;

    char* p = (char*)d_ws;
    auto alloc = [&](size_t bytes) { char* r = p; p += (bytes + 255) & ~(size_t)255; return r; };
    short* Hfhi   = (short*)alloc((size_t)2048*1728*2);
    short* Hfc1hi = (short*)alloc((size_t)2048*512*2);
    float* H      = (float*)alloc((size_t)2048*512*4);
    short* Hhi    = (short*)alloc((size_t)2048*512*2);
    float* An     = (float*)alloc((size_t)2048*512*4);
    short* H2hi   = (short*)alloc((size_t)2048*1024*2);
    float* St     = (float*)alloc((size_t)10*2048*4);
    float* minv   = (float*)alloc(10*2*4);
    float* embs   = (float*)alloc((size_t)10*1024*4);
    float* gpart  = (float*)alloc((size_t)10*128*4);
    short* w1m    = (short*)alloc(1536*2);
    short* w2mp   = (short*)alloc(16896*2);
    short* fc1whi = (short*)alloc((size_t)512*1728*2);
    short* fc2whi = (short*)alloc((size_t)512*512*2);
    short* nbrwhi = (short*)alloc((size_t)512*512*2);
    short* prwhi  = (short*)alloc((size_t)1024*1024*2);

    prep_all_kernel<<<9792, 256, 0, stream>>>(
        fc1_w, fc1whi, fc2_w, fc2whi, nbr_w, nbrwhi, proto_w, prwhi,
        conv1_w, w1m, conv2_w, w2mp, St, embs);

    conv_mfma_kernel<<<2048, 128, 0, stream>>>(x, w1m, conv1_b, w2mp, conv2_b, Hfhi);
    gemm_kernel<1,0,1,0><<<dim3(8,32), 512, 0, stream>>>(
        Hfhi, fc1whi, fc1_b, nullptr, Hfc1hi, nullptr, nullptr, 512, 1728);
    gemm_kernel<1,1,1,0><<<dim3(8,32), 512, 0, stream>>>(
        Hfc1hi, fc2whi, fc2_b, H, Hhi, nullptr, nullptr, 512, 512);
    gemm_kernel<2,1,0,0><<<dim3(8,32), 512, 0, stream>>>(
        Hhi, nbrwhi, nbr_b, An, nullptr, nullptr, nullptr, 512, 512);
    nbr_attn_kernel<<<2048, 64, 0, stream>>>(H, An, H2hi);
    gemm_kernel<2,0,0,1><<<dim3(16,32), 512, 0, stream>>>(
        H2hi, prwhi, proto_b, nullptr, nullptr, templ, St, 1024, 1024);
    beta_embs_kernel<<<dim3(32,10), 256, 0, stream>>>(St, H2hi, embs, minv);
    glob_g2_kernel<<<dim3(128,10), 64, 0, stream>>>(embs, glob_w1, glob_b1, glob_w2, gpart);
    final3_kernel<<<1, 256, 0, stream>>>(gpart, glob_b2, embs, St, minv, cls_w, cls_b, out);
}

// Round 17
// 136.156 us; speedup vs baseline: 1.3864x; 1.3864x over previous
//
#include <hip/hip_runtime.h>
#include <hip/hip_bf16.h>
#include <math.h>

// ---------------------------------------------------------------------------
// MAMIL round 17: revert conv to R15 exactly (best measured: 136.5us total).
// R16 lesson (repeat of R7 class): launch_bounds-demanded occupancy beyond
// what the register working set permits -> allocator squeeze (64 VGPR) ->
// scratch spills (175MB fetch + 97MB write), conv 33->85us. The K-packed
// conv's ~200-VGPR working set (33 B-frags + 11 A-frags) is intrinsic;
// 1 wave/image at 2 waves/SIMD is this design's validated optimum.
// ---------------------------------------------------------------------------

typedef short short8 __attribute__((ext_vector_type(8)));
typedef float f32x4  __attribute__((ext_vector_type(4)));

__device__ inline short f2bf(float f) {
    unsigned u = __builtin_bit_cast(unsigned, f);
    u += 0x7fff + ((u >> 16) & 1);
    return (short)(u >> 16);
}
__device__ inline float bf2f(short h) {
    unsigned u = ((unsigned)(unsigned short)h) << 16;
    return __builtin_bit_cast(float, u);
}
__device__ inline f32x4 mfma16(short8 a, short8 b, f32x4 c) {
    return __builtin_amdgcn_mfma_f32_16x16x32_bf16(a, b, c, 0, 0, 0);
}

// ---------------- fused weight prep + workspace zeroing (hi only) ----------------
__global__ __launch_bounds__(256) void prep_all_kernel(
    const float* __restrict__ fc1w, short* __restrict__ fc1whi,
    const float* __restrict__ fc2w, short* __restrict__ fc2whi,
    const float* __restrict__ nbrw, short* __restrict__ nbrwhi,
    const float* __restrict__ prw,  short* __restrict__ prwhi,
    const float* __restrict__ w1,   short* __restrict__ w1m,
    const float* __restrict__ w2,   short* __restrict__ w2mp,
    float* __restrict__ St, float* __restrict__ embs)
{
    const int b = blockIdx.x, tid = threadIdx.x;
    if (b < 3456) {
        int i = b*256 + tid; if (i < 884736) fc1whi[i] = f2bf(fc1w[i]);
    } else if (b < 4480) {
        int i = (b-3456)*256 + tid; if (i < 262144) fc2whi[i] = f2bf(fc2w[i]);
    } else if (b < 5504) {
        int i = (b-4480)*256 + tid; if (i < 262144) nbrwhi[i] = f2bf(nbrw[i]);
    } else if (b < 9600) {
        int i = (b-5504)*256 + tid; if (i < 1048576) prwhi[i] = f2bf(prw[i]);
    } else if (b < 9606) {
        int i = (b-9600)*256 + tid;
        if (i < 1536) {
            int c = i >> 5, k = i & 31;
            w1m[i] = (c < 36 && k < 16) ? f2bf(w1[c*16 + k]) : (short)0;
        }
    } else if (b < 9672) {
        // w2mp [48][352]: ks0-8 = tap=ks, ic=j (j<32); ks9 = tap=j>>2,
        // ic=32+(j&3); ks10 = (j<4) tap8 ic32+j else 0.
        int i = (b-9606)*256 + tid;
        if (i < 16896) {
            int oc = i / 352, r = i % 352, ks = r >> 5, j = r & 31;
            float v = 0.0f;
            if (ks < 9)          v = w2[oc*324 + j*9 + ks];
            else if (ks == 9)    v = w2[oc*324 + (32 + (j & 3))*9 + (j >> 2)];
            else if (j < 4)      v = w2[oc*324 + (32 + j)*9 + 8];
            w2mp[i] = f2bf(v);
        }
    } else if (b < 9752) {
        int i = (b-9672)*256 + tid; if (i < 20480) St[i] = 0.0f;
    } else {
        int i = (b-9752)*256 + tid; if (i < 10240) embs[i] = 0.0f;
    }
}

// ---------------- fused conv1+pool -> conv2+pool (1 wave = 1 image) ----------------
__global__ __launch_bounds__(64, 2) void conv_mfma_kernel(
    const float* __restrict__ x,     // [2048][1024]
    const short* __restrict__ w1m,   // [48][32]
    const float* __restrict__ b1,    // [36]
    const short* __restrict__ w2mp,  // [48][352] K-packed
    const float* __restrict__ b2,    // [48]
    short* __restrict__ Hfhi)        // [2048][1728], oc*36+r2
{
    __shared__ __align__(16) short sxb[2][1024];     // bf16(x) + shift-left-1 copy
    __shared__ __align__(16) short sh1[196*40];      // 80B rows (72B data)
    const int n = blockIdx.x, l = threadIdx.x;
    const int g = l >> 4, fr = l & 15;

    #pragma unroll
    for (int i = 0; i < 4; ++i) {
        const float4 v4 = ((const float4*)(x + (size_t)n*1024))[l + 64*i];
        short v[4] = { f2bf(v4.x), f2bf(v4.y), f2bf(v4.z), f2bf(v4.w) };
        const int c4 = (l + 64*i)*4;
        *(short4*)&sxb[0][c4] = *(short4*)v;
        if (c4 & 31) sxb[1][c4-1] = v[0];
        sxb[1][c4+0] = v[1];
        sxb[1][c4+1] = v[2];
        sxb[1][c4+2] = v[3];
    }
    short8 bw1[3];
    #pragma unroll
    for (int nt = 0; nt < 3; ++nt)
        bw1[nt] = *(const short8*)(w1m + (nt*16 + fr)*32 + g*8);
    short8 bfr[3][11];
    #pragma unroll
    for (int nt = 0; nt < 3; ++nt) {
        const short* wb = w2mp + (size_t)(nt*16 + fr)*352 + g*8;
        #pragma unroll
        for (int ks = 0; ks < 11; ++ks)
            bfr[nt][ks] = *(const short8*)(wb + ks*32);
    }
    __syncthreads();

    // ---- conv1 (1->36, 4x4, 32->29) + relu + 2x2 pool -> sh1 [196][36] ----
    for (int mt = 0; mt < 49; ++mt) {
        const int pp = mt*16 + fr;
        const int q = pp >> 2, dd = pp & 3;
        const int iy0 = 2*(q/14) + (dd >> 1), ix0 = 2*(q%14) + (dd & 1);
        short8 af = {};
        if (g < 2) {
            const int par = ix0 & 1;
            const int colp = ix0 - par;
            const unsigned* p0 = (const unsigned*)&sxb[par][(iy0 + 2*g)*32 + colp];
            union { unsigned u[4]; short8 s; } uu;
            uu.u[0] = p0[0];  uu.u[1] = p0[1];
            uu.u[2] = p0[16]; uu.u[3] = p0[17];
            af = uu.s;
        }
        f32x4 acc[3] = {};
        #pragma unroll
        for (int nt = 0; nt < 3; ++nt) acc[nt] = mfma16(af, bw1[nt], acc[nt]);
        const int q1 = mt*4 + g;          // pooled pos 0..195
        #pragma unroll
        for (int nt = 0; nt < 3; ++nt) {
            const int c = nt*16 + fr;
            if (c < 36) {
                float m = fmaxf(fmaxf(acc[nt][0], acc[nt][1]),
                                fmaxf(acc[nt][2], acc[nt][3]));
                m = fmaxf(m + b1[c], 0.0f);
                *(short*)((char*)sh1 + (q1*80 + c*2)) = f2bf(m);
            }
        }
    }
    __syncthreads();

    // ---- conv2: mt-outer; A-frags built once per mt, shared across 3 nt ----
    for (int mt = 0; mt < 9; ++mt) {
        const int pp = mt*16 + fr;
        const int q2 = pp >> 2, dd = pp & 3;
        const int oy = 2*(q2/6) + (dd >> 1), ox = 2*(q2%6) + (dd & 1);
        short8 av[11];
        #pragma unroll
        for (int tap = 0; tap < 9; ++tap) {
            const int hr = (oy + tap/3)*14 + ox + tap%3;
            av[tap] = *(const short8*)((char*)sh1 + (hr*80 + g*16));
        }
        {
            const int t0 = g*2, t1 = g*2 + 1;
            const int h0 = (oy + t0/3)*14 + ox + t0%3;
            const int h1 = (oy + t1/3)*14 + ox + t1%3;
            union { short4 h[2]; short8 s; } u9;
            u9.h[0] = *(const short4*)((char*)sh1 + (h0*80 + 64));
            u9.h[1] = *(const short4*)((char*)sh1 + (h1*80 + 64));
            av[9] = u9.s;
        }
        {
            short8 a10 = {};
            if (g == 0) {
                const int h8 = (oy + 2)*14 + ox + 2;
                *(short4*)&a10 = *(const short4*)((char*)sh1 + (h8*80 + 64));
            }
            av[10] = a10;
        }
        #pragma unroll
        for (int nt = 0; nt < 3; ++nt) {
            f32x4 acc = {};
            #pragma unroll
            for (int ks = 0; ks < 11; ++ks)
                acc = mfma16(av[ks], bfr[nt][ks], acc);
            const int oc = nt*16 + fr;
            float m = fmaxf(fmaxf(acc[0], acc[1]), fmaxf(acc[2], acc[3]));
            m = fmaxf(m + b2[oc], 0.0f);
            Hfhi[(size_t)n*1728 + oc*36 + (mt*4 + g)] = f2bf(m);
        }
    }
}

// ---------------- MFMA GEMM: C = act(A_hi @ W_hi^T + bias) ----------------
// 512 threads, double-buffered LDS, ONE barrier per K-step.
template<int ACT, int OUTF32, int OUTBF, int TSC>
__global__ __launch_bounds__(512, 2) void gemm_kernel(
    const short* __restrict__ Ahi, const short* __restrict__ Whi,
    const float* __restrict__ bias,
    float* __restrict__ Cf, short* __restrict__ Chi,
    const float* __restrict__ Tm, float* __restrict__ St,
    const int N, const int K)
{
    __shared__ __align__(16) short sA[2][4096];   // [buf][row*64+k], swz ((row&7)<<4)
    __shared__ __align__(16) short sB[2][4096];
    const int bn = blockIdx.x, bm = blockIdx.y;
    const int tid = threadIdx.x, l = tid & 63, w = tid >> 6, g = l >> 4, fr = l & 15;
    const int wm = w & 3, wn = w >> 2;
    const int srow = tid >> 3;              // 0..63
    const int wbyte = srow*128 + (tid & 7)*16;
    const int swb = (srow & 7) << 4;
    const size_t aoff = (size_t)(bm*64 + srow)*K + (tid & 7)*8;
    const size_t boff = (size_t)(bn*64 + srow)*K + (tid & 7)*8;
    f32x4 acc[2] = {};
    short8 ra = *(const short8*)(Ahi + aoff);
    short8 rb = *(const short8*)(Whi + boff);
    int cur = 0;
    for (int k0 = 0; k0 < K; k0 += 64) {
        *(short8*)((char*)&sA[cur][0] + (wbyte ^ swb)) = ra;
        *(short8*)((char*)&sB[cur][0] + (wbyte ^ swb)) = rb;
        __syncthreads();
        if (k0 + 64 < K) {
            ra = *(const short8*)(Ahi + aoff + k0 + 64);
            rb = *(const short8*)(Whi + boff + k0 + 64);
        }
        const int ar = wm*16 + fr, asw = (ar & 7) << 4;
        const short8 ah0 = *(const short8*)((char*)&sA[cur][0] + ((ar*128      + g*16) ^ asw));
        const short8 ah1 = *(const short8*)((char*)&sA[cur][0] + ((ar*128 + 64 + g*16) ^ asw));
        #pragma unroll
        for (int ntl = 0; ntl < 2; ++ntl) {
            const int br = (wn*2 + ntl)*16 + fr, bsw = (br & 7) << 4;
            const short8 bh0 = *(const short8*)((char*)&sB[cur][0] + ((br*128      + g*16) ^ bsw));
            const short8 bh1 = *(const short8*)((char*)&sB[cur][0] + ((br*128 + 64 + g*16) ^ bsw));
            acc[ntl] = mfma16(ah0, bh0, acc[ntl]);
            acc[ntl] = mfma16(ah1, bh1, acc[ntl]);
        }
        cur ^= 1;
    }
    float pv[2][4];
    #pragma unroll
    for (int ntl = 0; ntl < 2; ++ntl) {
        const int col = bn*64 + (wn*2 + ntl)*16 + fr;
        const float bv = bias[col];
        #pragma unroll
        for (int i = 0; i < 4; ++i) {
            const int row = bm*64 + wm*16 + g*4 + i;
            float v = acc[ntl][i] + bv;
            if (ACT == 1) v = fmaxf(v, 0.0f);
            if (ACT == 2) v = tanhf(v);
            pv[ntl][i] = v;
            const size_t idx = (size_t)row*N + col;
            if (OUTF32) Cf[idx] = v;
            if (OUTBF)  Chi[idx] = f2bf(v);
        }
    }
    if (TSC) {
        for (int t = 0; t < 10; ++t) {
            float tm[2];
            #pragma unroll
            for (int ntl = 0; ntl < 2; ++ntl)
                tm[ntl] = Tm[t*1024 + bn*64 + (wn*2 + ntl)*16 + fr];
            float part[4];
            #pragma unroll
            for (int i = 0; i < 4; ++i) {
                float s = 0.0f;
                #pragma unroll
                for (int ntl = 0; ntl < 2; ++ntl) s = fmaf(pv[ntl][i], tm[ntl], s);
                #pragma unroll
                for (int m = 1; m <= 8; m <<= 1) s += __shfl_xor(s, m);
                part[i] = s;
            }
            if (fr == 0) {
                #pragma unroll
                for (int i = 0; i < 4; ++i)
                    atomicAdd(&St[t*2048 + bm*64 + wm*16 + g*4 + i], part[i]);
            }
        }
    }
}

// ---------------- sparse neighborhood attention (ILP batched) ----------------
__global__ __launch_bounds__(64) void nbr_attn_kernel(
    const float* __restrict__ H, const float* __restrict__ An,
    short* __restrict__ H2hi)       // [2048][1024] bf16 hi only
{
    const int i = blockIdx.x;
    const int lane = threadIdx.x;
    const int r = i >> 6, c = i & 63;
    const int DR[8] = {-1,-1,-1, 0, 0, 1, 1, 1};
    const int DC[8] = {-1, 0, 1,-1, 1,-1, 0, 1};
    int nbr[8]; bool val[8];
    #pragma unroll
    for (int j = 0; j < 8; ++j) {
        const int rr = r + DR[j], cc = c + DC[j];
        val[j] = (rr >= 0 && rr < 32 && cc >= 0 && cc < 64);
        nbr[j] = val[j] ? rr*64 + cc : i;
    }
    float hi[8];
    #pragma unroll
    for (int q = 0; q < 8; ++q) hi[q] = H[(size_t)i*512 + q*64 + lane];
    float av[8][8];
    #pragma unroll
    for (int j = 0; j < 8; ++j) {
        const float* an = An + (size_t)nbr[j]*512 + lane;
        #pragma unroll
        for (int q = 0; q < 8; ++q) av[j][q] = an[q*64];
    }
    float lg[8];
    #pragma unroll
    for (int j = 0; j < 8; ++j) {
        float s = 0.0f;
        #pragma unroll
        for (int q = 0; q < 8; ++q) s = fmaf(hi[q], av[j][q], s);
        #pragma unroll
        for (int off = 32; off; off >>= 1) s += __shfl_xor(s, off);
        lg[j] = val[j] ? s : -1e30f;
    }
    float mx = -1e30f;
    #pragma unroll
    for (int j = 0; j < 8; ++j) mx = fmaxf(mx, lg[j]);
    float sum = 0.0f; float al[8];
    #pragma unroll
    for (int j = 0; j < 8; ++j) { al[j] = expf(lg[j]-mx); sum += al[j]; }
    const float inv = 1.0f/sum;
    #pragma unroll
    for (int j = 0; j < 8; ++j) {
        const float* hj = H + (size_t)nbr[j]*512 + lane;
        #pragma unroll
        for (int q = 0; q < 8; ++q) av[j][q] = hj[q*64];
    }
    float hn[8] = {};
    #pragma unroll
    for (int j = 0; j < 8; ++j) {
        const float a = al[j]*inv;
        #pragma unroll
        for (int q = 0; q < 8; ++q) hn[q] = fmaf(a, av[j][q], hn[q]);
    }
    #pragma unroll
    for (int q = 0; q < 8; ++q) {
        const size_t i0 = (size_t)i*1024 + q*64 + lane;
        H2hi[i0]       = f2bf(hi[q]);
        H2hi[i0 + 512] = f2bf(hn[q]);
    }
}

// ---------------- betas (from St) + embs partials; writes minv ----------------
__global__ __launch_bounds__(256) void beta_embs_kernel(
    const float* __restrict__ St,   // [10][2048]
    const short* __restrict__ H2hi, // [2048][1024] bf16
    float* __restrict__ embs,       // [10][1024] (zeroed)
    float* __restrict__ minv)       // [10][2] = {mx, inv}
{
    const int t = blockIdx.y;
    const int tid = threadIdx.x;
    __shared__ float red[256];
    __shared__ float sb[256];
    float mx = -1e30f;
    for (int n = tid; n < 2048; n += 256) mx = fmaxf(mx, St[t*2048+n]);
    red[tid] = mx; __syncthreads();
    for (int s = 128; s; s >>= 1) { if (tid < s) red[tid] = fmaxf(red[tid], red[tid+s]); __syncthreads(); }
    mx = red[0]; __syncthreads();
    float sum = 0.0f;
    for (int n = tid; n < 2048; n += 256) sum += expf(St[t*2048+n]-mx);
    red[tid] = sum; __syncthreads();
    for (int s = 128; s; s >>= 1) { if (tid < s) red[tid] += red[tid+s]; __syncthreads(); }
    const float inv = 1.0f/red[0];
    if (blockIdx.x == 0 && tid == 0) { minv[t*2+0] = mx; minv[t*2+1] = inv; }
    const int colc = blockIdx.x & 3;
    const int nc   = blockIdx.x >> 2;
    sb[tid] = expf(St[t*2048 + nc*256 + tid] - mx) * inv;
    __syncthreads();
    const int col = colc*256 + tid;
    float acc = 0.0f;
    for (int j = 0; j < 256; ++j)
        acc = fmaf(sb[j], bf2f(H2hi[(size_t)(nc*256+j)*1024 + col]), acc);
    atomicAdd(&embs[t*1024+col], acc);
}

// ---------------- gpart[t,k] = tanh(embs[t].gw1[k]+gb1[k])*gw2[k] ----------------
__global__ __launch_bounds__(64) void glob_g2_kernel(
    const float* __restrict__ embs, const float* __restrict__ gw1,
    const float* __restrict__ gb1, const float* __restrict__ gw2,
    float* __restrict__ gpart)      // [10][128]
{
    const int k = blockIdx.x, t = blockIdx.y, lane = threadIdx.x;
    const float* e  = embs + t*1024 + lane;
    const float* wv = gw1 + k*1024 + lane;
    float s = 0.0f;
    #pragma unroll
    for (int q = 0; q < 16; ++q) s = fmaf(e[q*64], wv[q*64], s);
    #pragma unroll
    for (int off = 32; off; off >>= 1) s += __shfl_xor(s, off);
    if (lane == 0) gpart[t*128 + k] = tanhf(s + gb1[k]) * gw2[k];
}

// ---------------- gamma softmax + M + A + classifier ----------------
__global__ __launch_bounds__(256) void final3_kernel(
    const float* __restrict__ gpart, const float* __restrict__ gb2,
    const float* __restrict__ embs,  const float* __restrict__ St,
    const float* __restrict__ minv,
    const float* __restrict__ cw, const float* __restrict__ cb,
    float* __restrict__ out)         // [2051] = Y_prob[2], Y_hat[1], A[2048]
{
    __shared__ float gam[10];
    __shared__ float sM[1024];
    __shared__ float red[256];
    __shared__ float gv[10];
    __shared__ float smx[10], sinv[10];
    __shared__ float v0s;
    const int tid = threadIdx.x;
    for (int t = 0; t < 10; ++t) {
        float s = (tid < 128) ? gpart[t*128 + tid] : 0.0f;
        red[tid] = s; __syncthreads();
        for (int st = 128; st; st >>= 1) { if (tid < st) red[tid] += red[tid+st]; __syncthreads(); }
        if (tid == 0) gv[t] = red[0];
        __syncthreads();
    }
    if (tid < 10) { smx[tid] = minv[tid*2]; sinv[tid] = minv[tid*2+1]; }
    if (tid == 0) {
        float mx = -1e30f;
        for (int t = 0; t < 10; ++t) mx = fmaxf(mx, gv[t] + gb2[0]);
        float sum = 0.0f;
        for (int t = 0; t < 10; ++t) { gam[t] = expf(gv[t] + gb2[0] - mx); sum += gam[t]; }
        for (int t = 0; t < 10; ++t) gam[t] /= sum;
    }
    __syncthreads();
    for (int col = tid; col < 1024; col += 256) {
        float m = 0.0f;
        for (int t = 0; t < 10; ++t) m = fmaf(gam[t], embs[t*1024+col], m);
        sM[col] = m;
    }
    for (int n = tid; n < 2048; n += 256) {
        float a = 0.0f;
        for (int t = 0; t < 10; ++t)
            a = fmaf(gam[t], expf(St[t*2048+n]-smx[t])*sinv[t], a);
        out[3+n] = a;
    }
    __syncthreads();
    float s0 = 0.0f, s1 = 0.0f;
    for (int q = tid; q < 1024; q += 256) {
        s0 = fmaf(sM[q], cw[q], s0);
        s1 = fmaf(sM[q], cw[1024+q], s1);
    }
    red[tid] = s0; __syncthreads();
    for (int s = 128; s; s >>= 1) { if (tid < s) red[tid] += red[tid+s]; __syncthreads(); }
    if (tid == 0) v0s = red[0];
    __syncthreads();
    red[tid] = s1; __syncthreads();
    for (int s = 128; s; s >>= 1) { if (tid < s) red[tid] += red[tid+s]; __syncthreads(); }
    if (tid == 0) {
        const float l0 = v0s + cb[0], l1 = red[0] + cb[1];
        const float p0 = 1.0f/(1.0f+expf(-l0));
        const float p1 = 1.0f/(1.0f+expf(-l1));
        out[0] = p0; out[1] = p1;
        out[2] = (p1 > p0) ? 1.0f : 0.0f;
    }
}

extern "C" void kernel_launch(void* const* d_in, const int* in_sizes, int n_in,
                              void* d_out, int out_size, void* d_ws, size_t ws_size,
                              hipStream_t stream)
{
    (void)in_sizes; (void)n_in; (void)out_size; (void)ws_size;
    const float* x        = (const float*)d_in[0];
    const float* conv1_w  = (const float*)d_in[2];
    const float* conv1_b  = (const float*)d_in[3];
    const float* conv2_w  = (const float*)d_in[4];
    const float* conv2_b  = (const float*)d_in[5];
    const float* fc1_w    = (const float*)d_in[6];
    const float* fc1_b    = (const float*)d_in[7];
    const float* fc2_w    = (const float*)d_in[8];
    const float* fc2_b    = (const float*)d_in[9];
    const float* nbr_w    = (const float*)d_in[10];
    const float* nbr_b    = (const float*)d_in[11];
    const float* templ    = (const float*)d_in[12];
    const float* proto_w  = (const float*)d_in[13];
    const float* proto_b  = (const float*)d_in[14];
    const float* glob_w1  = (const float*)d_in[15];
    const float* glob_b1  = (const float*)d_in[16];
    const float* glob_w2  = (const float*)d_in[17];
    const float* glob_b2  = (const float*)d_in[18];
    const float* cls_w    = (const float*)d_in[19];
    const float* cls_b    = (const float*)d_in[20];
    float* out = (float*)d_out;

    char* p = (char*)d_ws;
    auto alloc = [&](size_t bytes) { char* r = p; p += (bytes + 255) & ~(size_t)255; return r; };
    short* Hfhi   = (short*)alloc((size_t)2048*1728*2);
    short* Hfc1hi = (short*)alloc((size_t)2048*512*2);
    float* H      = (float*)alloc((size_t)2048*512*4);
    short* Hhi    = (short*)alloc((size_t)2048*512*2);
    float* An     = (float*)alloc((size_t)2048*512*4);
    short* H2hi   = (short*)alloc((size_t)2048*1024*2);
    float* St     = (float*)alloc((size_t)10*2048*4);
    float* minv   = (float*)alloc(10*2*4);
    float* embs   = (float*)alloc((size_t)10*1024*4);
    float* gpart  = (float*)alloc((size_t)10*128*4);
    short* w1m    = (short*)alloc(1536*2);
    short* w2mp   = (short*)alloc(16896*2);
    short* fc1whi = (short*)alloc((size_t)512*1728*2);
    short* fc2whi = (short*)alloc((size_t)512*512*2);
    short* nbrwhi = (short*)alloc((size_t)512*512*2);
    short* prwhi  = (short*)alloc((size_t)1024*1024*2);

    prep_all_kernel<<<9792, 256, 0, stream>>>(
        fc1_w, fc1whi, fc2_w, fc2whi, nbr_w, nbrwhi, proto_w, prwhi,
        conv1_w, w1m, conv2_w, w2mp, St, embs);

    conv_mfma_kernel<<<2048, 64, 0, stream>>>(x, w1m, conv1_b, w2mp, conv2_b, Hfhi);
    gemm_kernel<1,0,1,0><<<dim3(8,32), 512, 0, stream>>>(
        Hfhi, fc1whi, fc1_b, nullptr, Hfc1hi, nullptr, nullptr, 512, 1728);
    gemm_kernel<1,1,1,0><<<dim3(8,32), 512, 0, stream>>>(
        Hfc1hi, fc2whi, fc2_b, H, Hhi, nullptr, nullptr, 512, 512);
    gemm_kernel<2,1,0,0><<<dim3(8,32), 512, 0, stream>>>(
        Hhi, nbrwhi, nbr_b, An, nullptr, nullptr, nullptr, 512, 512);
    nbr_attn_kernel<<<2048, 64, 0, stream>>>(H, An, H2hi);
    gemm_kernel<2,0,0,1><<<dim3(16,32), 512, 0, stream>>>(
        H2hi, prwhi, proto_b, nullptr, nullptr, templ, St, 1024, 1024);
    beta_embs_kernel<<<dim3(32,10), 256, 0, stream>>>(St, H2hi, embs, minv);
    glob_g2_kernel<<<dim3(128,10), 64, 0, stream>>>(embs, glob_w1, glob_b1, glob_w2, gpart);
    final3_kernel<<<1, 256, 0, stream>>>(gpart, glob_b2, embs, St, minv, cls_w, cls_b, out);
}

// Round 18
// 134.237 us; speedup vs baseline: 1.4063x; 1.0143x over previous
//
#include <hip/hip_runtime.h>
#include <hip/hip_bf16.h>
#include <math.h>

// ---------------------------------------------------------------------------
// MAMIL round 18: bf16 end-to-end through the neighbor-attention path.
//  - fc2 GEMM drops f32 H write (H existed only for nbr_attn).
//  - nbr GEMM writes An as bf16.
//  - nbr_attn reads Hhi/Anhi (bf16): ~16MB gather traffic halved; H2hi "hi"
//    half is a bit-identical pass-through; only Hn drifts (~0.3% on alphas).
// conv / GEMM core / tail identical to R17 (136.2us, absmax 3.9e-3).
// ---------------------------------------------------------------------------

typedef short short8 __attribute__((ext_vector_type(8)));
typedef float f32x4  __attribute__((ext_vector_type(4)));

__device__ inline short f2bf(float f) {
    unsigned u = __builtin_bit_cast(unsigned, f);
    u += 0x7fff + ((u >> 16) & 1);
    return (short)(u >> 16);
}
__device__ inline float bf2f(short h) {
    unsigned u = ((unsigned)(unsigned short)h) << 16;
    return __builtin_bit_cast(float, u);
}
__device__ inline f32x4 mfma16(short8 a, short8 b, f32x4 c) {
    return __builtin_amdgcn_mfma_f32_16x16x32_bf16(a, b, c, 0, 0, 0);
}

// ---------------- fused weight prep + workspace zeroing (hi only) ----------------
__global__ __launch_bounds__(256) void prep_all_kernel(
    const float* __restrict__ fc1w, short* __restrict__ fc1whi,
    const float* __restrict__ fc2w, short* __restrict__ fc2whi,
    const float* __restrict__ nbrw, short* __restrict__ nbrwhi,
    const float* __restrict__ prw,  short* __restrict__ prwhi,
    const float* __restrict__ w1,   short* __restrict__ w1m,
    const float* __restrict__ w2,   short* __restrict__ w2mp,
    float* __restrict__ St, float* __restrict__ embs)
{
    const int b = blockIdx.x, tid = threadIdx.x;
    if (b < 3456) {
        int i = b*256 + tid; if (i < 884736) fc1whi[i] = f2bf(fc1w[i]);
    } else if (b < 4480) {
        int i = (b-3456)*256 + tid; if (i < 262144) fc2whi[i] = f2bf(fc2w[i]);
    } else if (b < 5504) {
        int i = (b-4480)*256 + tid; if (i < 262144) nbrwhi[i] = f2bf(nbrw[i]);
    } else if (b < 9600) {
        int i = (b-5504)*256 + tid; if (i < 1048576) prwhi[i] = f2bf(prw[i]);
    } else if (b < 9606) {
        int i = (b-9600)*256 + tid;
        if (i < 1536) {
            int c = i >> 5, k = i & 31;
            w1m[i] = (c < 36 && k < 16) ? f2bf(w1[c*16 + k]) : (short)0;
        }
    } else if (b < 9672) {
        int i = (b-9606)*256 + tid;
        if (i < 16896) {
            int oc = i / 352, r = i % 352, ks = r >> 5, j = r & 31;
            float v = 0.0f;
            if (ks < 9)          v = w2[oc*324 + j*9 + ks];
            else if (ks == 9)    v = w2[oc*324 + (32 + (j & 3))*9 + (j >> 2)];
            else if (j < 4)      v = w2[oc*324 + (32 + j)*9 + 8];
            w2mp[i] = f2bf(v);
        }
    } else if (b < 9752) {
        int i = (b-9672)*256 + tid; if (i < 20480) St[i] = 0.0f;
    } else {
        int i = (b-9752)*256 + tid; if (i < 10240) embs[i] = 0.0f;
    }
}

// ---------------- fused conv1+pool -> conv2+pool (1 wave = 1 image) ----------------
__global__ __launch_bounds__(64, 2) void conv_mfma_kernel(
    const float* __restrict__ x,     // [2048][1024]
    const short* __restrict__ w1m,   // [48][32]
    const float* __restrict__ b1,    // [36]
    const short* __restrict__ w2mp,  // [48][352] K-packed
    const float* __restrict__ b2,    // [48]
    short* __restrict__ Hfhi)        // [2048][1728], oc*36+r2
{
    __shared__ __align__(16) short sxb[2][1024];     // bf16(x) + shift-left-1 copy
    __shared__ __align__(16) short sh1[196*40];      // 80B rows (72B data)
    const int n = blockIdx.x, l = threadIdx.x;
    const int g = l >> 4, fr = l & 15;

    #pragma unroll
    for (int i = 0; i < 4; ++i) {
        const float4 v4 = ((const float4*)(x + (size_t)n*1024))[l + 64*i];
        short v[4] = { f2bf(v4.x), f2bf(v4.y), f2bf(v4.z), f2bf(v4.w) };
        const int c4 = (l + 64*i)*4;
        *(short4*)&sxb[0][c4] = *(short4*)v;
        if (c4 & 31) sxb[1][c4-1] = v[0];
        sxb[1][c4+0] = v[1];
        sxb[1][c4+1] = v[2];
        sxb[1][c4+2] = v[3];
    }
    short8 bw1[3];
    #pragma unroll
    for (int nt = 0; nt < 3; ++nt)
        bw1[nt] = *(const short8*)(w1m + (nt*16 + fr)*32 + g*8);
    short8 bfr[3][11];
    #pragma unroll
    for (int nt = 0; nt < 3; ++nt) {
        const short* wb = w2mp + (size_t)(nt*16 + fr)*352 + g*8;
        #pragma unroll
        for (int ks = 0; ks < 11; ++ks)
            bfr[nt][ks] = *(const short8*)(wb + ks*32);
    }
    __syncthreads();

    // ---- conv1 (1->36, 4x4, 32->29) + relu + 2x2 pool -> sh1 [196][36] ----
    for (int mt = 0; mt < 49; ++mt) {
        const int pp = mt*16 + fr;
        const int q = pp >> 2, dd = pp & 3;
        const int iy0 = 2*(q/14) + (dd >> 1), ix0 = 2*(q%14) + (dd & 1);
        short8 af = {};
        if (g < 2) {
            const int par = ix0 & 1;
            const int colp = ix0 - par;
            const unsigned* p0 = (const unsigned*)&sxb[par][(iy0 + 2*g)*32 + colp];
            union { unsigned u[4]; short8 s; } uu;
            uu.u[0] = p0[0];  uu.u[1] = p0[1];
            uu.u[2] = p0[16]; uu.u[3] = p0[17];
            af = uu.s;
        }
        f32x4 acc[3] = {};
        #pragma unroll
        for (int nt = 0; nt < 3; ++nt) acc[nt] = mfma16(af, bw1[nt], acc[nt]);
        const int q1 = mt*4 + g;          // pooled pos 0..195
        #pragma unroll
        for (int nt = 0; nt < 3; ++nt) {
            const int c = nt*16 + fr;
            if (c < 36) {
                float m = fmaxf(fmaxf(acc[nt][0], acc[nt][1]),
                                fmaxf(acc[nt][2], acc[nt][3]));
                m = fmaxf(m + b1[c], 0.0f);
                *(short*)((char*)sh1 + (q1*80 + c*2)) = f2bf(m);
            }
        }
    }
    __syncthreads();

    // ---- conv2: mt-outer; A-frags built once per mt, shared across 3 nt ----
    for (int mt = 0; mt < 9; ++mt) {
        const int pp = mt*16 + fr;
        const int q2 = pp >> 2, dd = pp & 3;
        const int oy = 2*(q2/6) + (dd >> 1), ox = 2*(q2%6) + (dd & 1);
        short8 av[11];
        #pragma unroll
        for (int tap = 0; tap < 9; ++tap) {
            const int hr = (oy + tap/3)*14 + ox + tap%3;
            av[tap] = *(const short8*)((char*)sh1 + (hr*80 + g*16));
        }
        {
            const int t0 = g*2, t1 = g*2 + 1;
            const int h0 = (oy + t0/3)*14 + ox + t0%3;
            const int h1 = (oy + t1/3)*14 + ox + t1%3;
            union { short4 h[2]; short8 s; } u9;
            u9.h[0] = *(const short4*)((char*)sh1 + (h0*80 + 64));
            u9.h[1] = *(const short4*)((char*)sh1 + (h1*80 + 64));
            av[9] = u9.s;
        }
        {
            short8 a10 = {};
            if (g == 0) {
                const int h8 = (oy + 2)*14 + ox + 2;
                *(short4*)&a10 = *(const short4*)((char*)sh1 + (h8*80 + 64));
            }
            av[10] = a10;
        }
        #pragma unroll
        for (int nt = 0; nt < 3; ++nt) {
            f32x4 acc = {};
            #pragma unroll
            for (int ks = 0; ks < 11; ++ks)
                acc = mfma16(av[ks], bfr[nt][ks], acc);
            const int oc = nt*16 + fr;
            float m = fmaxf(fmaxf(acc[0], acc[1]), fmaxf(acc[2], acc[3]));
            m = fmaxf(m + b2[oc], 0.0f);
            Hfhi[(size_t)n*1728 + oc*36 + (mt*4 + g)] = f2bf(m);
        }
    }
}

// ---------------- MFMA GEMM: C = act(A_hi @ W_hi^T + bias) ----------------
// 512 threads, double-buffered LDS, ONE barrier per K-step.
template<int ACT, int OUTF32, int OUTBF, int TSC>
__global__ __launch_bounds__(512, 2) void gemm_kernel(
    const short* __restrict__ Ahi, const short* __restrict__ Whi,
    const float* __restrict__ bias,
    float* __restrict__ Cf, short* __restrict__ Chi,
    const float* __restrict__ Tm, float* __restrict__ St,
    const int N, const int K)
{
    __shared__ __align__(16) short sA[2][4096];   // [buf][row*64+k], swz ((row&7)<<4)
    __shared__ __align__(16) short sB[2][4096];
    const int bn = blockIdx.x, bm = blockIdx.y;
    const int tid = threadIdx.x, l = tid & 63, w = tid >> 6, g = l >> 4, fr = l & 15;
    const int wm = w & 3, wn = w >> 2;
    const int srow = tid >> 3;              // 0..63
    const int wbyte = srow*128 + (tid & 7)*16;
    const int swb = (srow & 7) << 4;
    const size_t aoff = (size_t)(bm*64 + srow)*K + (tid & 7)*8;
    const size_t boff = (size_t)(bn*64 + srow)*K + (tid & 7)*8;
    f32x4 acc[2] = {};
    short8 ra = *(const short8*)(Ahi + aoff);
    short8 rb = *(const short8*)(Whi + boff);
    int cur = 0;
    for (int k0 = 0; k0 < K; k0 += 64) {
        *(short8*)((char*)&sA[cur][0] + (wbyte ^ swb)) = ra;
        *(short8*)((char*)&sB[cur][0] + (wbyte ^ swb)) = rb;
        __syncthreads();
        if (k0 + 64 < K) {
            ra = *(const short8*)(Ahi + aoff + k0 + 64);
            rb = *(const short8*)(Whi + boff + k0 + 64);
        }
        const int ar = wm*16 + fr, asw = (ar & 7) << 4;
        const short8 ah0 = *(const short8*)((char*)&sA[cur][0] + ((ar*128      + g*16) ^ asw));
        const short8 ah1 = *(const short8*)((char*)&sA[cur][0] + ((ar*128 + 64 + g*16) ^ asw));
        #pragma unroll
        for (int ntl = 0; ntl < 2; ++ntl) {
            const int br = (wn*2 + ntl)*16 + fr, bsw = (br & 7) << 4;
            const short8 bh0 = *(const short8*)((char*)&sB[cur][0] + ((br*128      + g*16) ^ bsw));
            const short8 bh1 = *(const short8*)((char*)&sB[cur][0] + ((br*128 + 64 + g*16) ^ bsw));
            acc[ntl] = mfma16(ah0, bh0, acc[ntl]);
            acc[ntl] = mfma16(ah1, bh1, acc[ntl]);
        }
        cur ^= 1;
    }
    float pv[2][4];
    #pragma unroll
    for (int ntl = 0; ntl < 2; ++ntl) {
        const int col = bn*64 + (wn*2 + ntl)*16 + fr;
        const float bv = bias[col];
        #pragma unroll
        for (int i = 0; i < 4; ++i) {
            const int row = bm*64 + wm*16 + g*4 + i;
            float v = acc[ntl][i] + bv;
            if (ACT == 1) v = fmaxf(v, 0.0f);
            if (ACT == 2) v = tanhf(v);
            pv[ntl][i] = v;
            const size_t idx = (size_t)row*N + col;
            if (OUTF32) Cf[idx] = v;
            if (OUTBF)  Chi[idx] = f2bf(v);
        }
    }
    if (TSC) {
        for (int t = 0; t < 10; ++t) {
            float tm[2];
            #pragma unroll
            for (int ntl = 0; ntl < 2; ++ntl)
                tm[ntl] = Tm[t*1024 + bn*64 + (wn*2 + ntl)*16 + fr];
            float part[4];
            #pragma unroll
            for (int i = 0; i < 4; ++i) {
                float s = 0.0f;
                #pragma unroll
                for (int ntl = 0; ntl < 2; ++ntl) s = fmaf(pv[ntl][i], tm[ntl], s);
                #pragma unroll
                for (int m = 1; m <= 8; m <<= 1) s += __shfl_xor(s, m);
                part[i] = s;
            }
            if (fr == 0) {
                #pragma unroll
                for (int i = 0; i < 4; ++i)
                    atomicAdd(&St[t*2048 + bm*64 + wm*16 + g*4 + i], part[i]);
            }
        }
    }
}

// ---------------- sparse neighborhood attention (bf16 in, ILP batched) ----------------
__global__ __launch_bounds__(64) void nbr_attn_kernel(
    const short* __restrict__ Hhi,  // [2048][512] bf16
    const short* __restrict__ Anhi, // [2048][512] bf16
    short* __restrict__ H2hi)       // [2048][1024] bf16
{
    const int i = blockIdx.x;
    const int lane = threadIdx.x;
    const int r = i >> 6, c = i & 63;
    const int DR[8] = {-1,-1,-1, 0, 0, 1, 1, 1};
    const int DC[8] = {-1, 0, 1,-1, 1,-1, 0, 1};
    int nbr[8]; bool val[8];
    #pragma unroll
    for (int j = 0; j < 8; ++j) {
        const int rr = r + DR[j], cc = c + DC[j];
        val[j] = (rr >= 0 && rr < 32 && cc >= 0 && cc < 64);
        nbr[j] = val[j] ? rr*64 + cc : i;
    }
    short hraw[8];
    float hi[8];
    #pragma unroll
    for (int q = 0; q < 8; ++q) {
        hraw[q] = Hhi[(size_t)i*512 + q*64 + lane];
        hi[q] = bf2f(hraw[q]);
    }
    float av[8][8];
    #pragma unroll
    for (int j = 0; j < 8; ++j) {
        const short* an = Anhi + (size_t)nbr[j]*512 + lane;
        #pragma unroll
        for (int q = 0; q < 8; ++q) av[j][q] = bf2f(an[q*64]);
    }
    float lg[8];
    #pragma unroll
    for (int j = 0; j < 8; ++j) {
        float s = 0.0f;
        #pragma unroll
        for (int q = 0; q < 8; ++q) s = fmaf(hi[q], av[j][q], s);
        #pragma unroll
        for (int off = 32; off; off >>= 1) s += __shfl_xor(s, off);
        lg[j] = val[j] ? s : -1e30f;
    }
    float mx = -1e30f;
    #pragma unroll
    for (int j = 0; j < 8; ++j) mx = fmaxf(mx, lg[j]);
    float sum = 0.0f; float al[8];
    #pragma unroll
    for (int j = 0; j < 8; ++j) { al[j] = expf(lg[j]-mx); sum += al[j]; }
    const float inv = 1.0f/sum;
    #pragma unroll
    for (int j = 0; j < 8; ++j) {
        const short* hj = Hhi + (size_t)nbr[j]*512 + lane;
        #pragma unroll
        for (int q = 0; q < 8; ++q) av[j][q] = bf2f(hj[q*64]);
    }
    float hn[8] = {};
    #pragma unroll
    for (int j = 0; j < 8; ++j) {
        const float a = al[j]*inv;
        #pragma unroll
        for (int q = 0; q < 8; ++q) hn[q] = fmaf(a, av[j][q], hn[q]);
    }
    #pragma unroll
    for (int q = 0; q < 8; ++q) {
        const size_t i0 = (size_t)i*1024 + q*64 + lane;
        H2hi[i0]       = hraw[q];           // bit-identical pass-through
        H2hi[i0 + 512] = f2bf(hn[q]);
    }
}

// ---------------- betas (from St) + embs partials; writes minv ----------------
__global__ __launch_bounds__(256) void beta_embs_kernel(
    const float* __restrict__ St,   // [10][2048]
    const short* __restrict__ H2hi, // [2048][1024] bf16
    float* __restrict__ embs,       // [10][1024] (zeroed)
    float* __restrict__ minv)       // [10][2] = {mx, inv}
{
    const int t = blockIdx.y;
    const int tid = threadIdx.x;
    __shared__ float red[256];
    __shared__ float sb[256];
    float mx = -1e30f;
    for (int n = tid; n < 2048; n += 256) mx = fmaxf(mx, St[t*2048+n]);
    red[tid] = mx; __syncthreads();
    for (int s = 128; s; s >>= 1) { if (tid < s) red[tid] = fmaxf(red[tid], red[tid+s]); __syncthreads(); }
    mx = red[0]; __syncthreads();
    float sum = 0.0f;
    for (int n = tid; n < 2048; n += 256) sum += expf(St[t*2048+n]-mx);
    red[tid] = sum; __syncthreads();
    for (int s = 128; s; s >>= 1) { if (tid < s) red[tid] += red[tid+s]; __syncthreads(); }
    const float inv = 1.0f/red[0];
    if (blockIdx.x == 0 && tid == 0) { minv[t*2+0] = mx; minv[t*2+1] = inv; }
    const int colc = blockIdx.x & 3;
    const int nc   = blockIdx.x >> 2;
    sb[tid] = expf(St[t*2048 + nc*256 + tid] - mx) * inv;
    __syncthreads();
    const int col = colc*256 + tid;
    float acc = 0.0f;
    for (int j = 0; j < 256; ++j)
        acc = fmaf(sb[j], bf2f(H2hi[(size_t)(nc*256+j)*1024 + col]), acc);
    atomicAdd(&embs[t*1024+col], acc);
}

// ---------------- gpart[t,k] = tanh(embs[t].gw1[k]+gb1[k])*gw2[k] ----------------
__global__ __launch_bounds__(64) void glob_g2_kernel(
    const float* __restrict__ embs, const float* __restrict__ gw1,
    const float* __restrict__ gb1, const float* __restrict__ gw2,
    float* __restrict__ gpart)      // [10][128]
{
    const int k = blockIdx.x, t = blockIdx.y, lane = threadIdx.x;
    const float* e  = embs + t*1024 + lane;
    const float* wv = gw1 + k*1024 + lane;
    float s = 0.0f;
    #pragma unroll
    for (int q = 0; q < 16; ++q) s = fmaf(e[q*64], wv[q*64], s);
    #pragma unroll
    for (int off = 32; off; off >>= 1) s += __shfl_xor(s, off);
    if (lane == 0) gpart[t*128 + k] = tanhf(s + gb1[k]) * gw2[k];
}

// ---------------- gamma softmax + M + A + classifier ----------------
__global__ __launch_bounds__(256) void final3_kernel(
    const float* __restrict__ gpart, const float* __restrict__ gb2,
    const float* __restrict__ embs,  const float* __restrict__ St,
    const float* __restrict__ minv,
    const float* __restrict__ cw, const float* __restrict__ cb,
    float* __restrict__ out)         // [2051] = Y_prob[2], Y_hat[1], A[2048]
{
    __shared__ float gam[10];
    __shared__ float sM[1024];
    __shared__ float red[256];
    __shared__ float gv[10];
    __shared__ float smx[10], sinv[10];
    __shared__ float v0s;
    const int tid = threadIdx.x;
    for (int t = 0; t < 10; ++t) {
        float s = (tid < 128) ? gpart[t*128 + tid] : 0.0f;
        red[tid] = s; __syncthreads();
        for (int st = 128; st; st >>= 1) { if (tid < st) red[tid] += red[tid+st]; __syncthreads(); }
        if (tid == 0) gv[t] = red[0];
        __syncthreads();
    }
    if (tid < 10) { smx[tid] = minv[tid*2]; sinv[tid] = minv[tid*2+1]; }
    if (tid == 0) {
        float mx = -1e30f;
        for (int t = 0; t < 10; ++t) mx = fmaxf(mx, gv[t] + gb2[0]);
        float sum = 0.0f;
        for (int t = 0; t < 10; ++t) { gam[t] = expf(gv[t] + gb2[0] - mx); sum += gam[t]; }
        for (int t = 0; t < 10; ++t) gam[t] /= sum;
    }
    __syncthreads();
    for (int col = tid; col < 1024; col += 256) {
        float m = 0.0f;
        for (int t = 0; t < 10; ++t) m = fmaf(gam[t], embs[t*1024+col], m);
        sM[col] = m;
    }
    for (int n = tid; n < 2048; n += 256) {
        float a = 0.0f;
        for (int t = 0; t < 10; ++t)
            a = fmaf(gam[t], expf(St[t*2048+n]-smx[t])*sinv[t], a);
        out[3+n] = a;
    }
    __syncthreads();
    float s0 = 0.0f, s1 = 0.0f;
    for (int q = tid; q < 1024; q += 256) {
        s0 = fmaf(sM[q], cw[q], s0);
        s1 = fmaf(sM[q], cw[1024+q], s1);
    }
    red[tid] = s0; __syncthreads();
    for (int s = 128; s; s >>= 1) { if (tid < s) red[tid] += red[tid+s]; __syncthreads(); }
    if (tid == 0) v0s = red[0];
    __syncthreads();
    red[tid] = s1; __syncthreads();
    for (int s = 128; s; s >>= 1) { if (tid < s) red[tid] += red[tid+s]; __syncthreads(); }
    if (tid == 0) {
        const float l0 = v0s + cb[0], l1 = red[0] + cb[1];
        const float p0 = 1.0f/(1.0f+expf(-l0));
        const float p1 = 1.0f/(1.0f+expf(-l1));
        out[0] = p0; out[1] = p1;
        out[2] = (p1 > p0) ? 1.0f : 0.0f;
    }
}

extern "C" void kernel_launch(void* const* d_in, const int* in_sizes, int n_in,
                              void* d_out, int out_size, void* d_ws, size_t ws_size,
                              hipStream_t stream)
{
    (void)in_sizes; (void)n_in; (void)out_size; (void)ws_size;
    const float* x        = (const float*)d_in[0];
    const float* conv1_w  = (const float*)d_in[2];
    const float* conv1_b  = (const float*)d_in[3];
    const float* conv2_w  = (const float*)d_in[4];
    const float* conv2_b  = (const float*)d_in[5];
    const float* fc1_w    = (const float*)d_in[6];
    const float* fc1_b    = (const float*)d_in[7];
    const float* fc2_w    = (const float*)d_in[8];
    const float* fc2_b    = (const float*)d_in[9];
    const float* nbr_w    = (const float*)d_in[10];
    const float* nbr_b    = (const float*)d_in[11];
    const float* templ    = (const float*)d_in[12];
    const float* proto_w  = (const float*)d_in[13];
    const float* proto_b  = (const float*)d_in[14];
    const float* glob_w1  = (const float*)d_in[15];
    const float* glob_b1  = (const float*)d_in[16];
    const float* glob_w2  = (const float*)d_in[17];
    const float* glob_b2  = (const float*)d_in[18];
    const float* cls_w    = (const float*)d_in[19];
    const float* cls_b    = (const float*)d_in[20];
    float* out = (float*)d_out;

    char* p = (char*)d_ws;
    auto alloc = [&](size_t bytes) { char* r = p; p += (bytes + 255) & ~(size_t)255; return r; };
    short* Hfhi   = (short*)alloc((size_t)2048*1728*2);
    short* Hfc1hi = (short*)alloc((size_t)2048*512*2);
    short* Hhi    = (short*)alloc((size_t)2048*512*2);
    short* Anhi   = (short*)alloc((size_t)2048*512*2);
    short* H2hi   = (short*)alloc((size_t)2048*1024*2);
    float* St     = (float*)alloc((size_t)10*2048*4);
    float* minv   = (float*)alloc(10*2*4);
    float* embs   = (float*)alloc((size_t)10*1024*4);
    float* gpart  = (float*)alloc((size_t)10*128*4);
    short* w1m    = (short*)alloc(1536*2);
    short* w2mp   = (short*)alloc(16896*2);
    short* fc1whi = (short*)alloc((size_t)512*1728*2);
    short* fc2whi = (short*)alloc((size_t)512*512*2);
    short* nbrwhi = (short*)alloc((size_t)512*512*2);
    short* prwhi  = (short*)alloc((size_t)1024*1024*2);

    prep_all_kernel<<<9792, 256, 0, stream>>>(
        fc1_w, fc1whi, fc2_w, fc2whi, nbr_w, nbrwhi, proto_w, prwhi,
        conv1_w, w1m, conv2_w, w2mp, St, embs);

    conv_mfma_kernel<<<2048, 64, 0, stream>>>(x, w1m, conv1_b, w2mp, conv2_b, Hfhi);
    gemm_kernel<1,0,1,0><<<dim3(8,32), 512, 0, stream>>>(
        Hfhi, fc1whi, fc1_b, nullptr, Hfc1hi, nullptr, nullptr, 512, 1728);
    gemm_kernel<1,0,1,0><<<dim3(8,32), 512, 0, stream>>>(
        Hfc1hi, fc2whi, fc2_b, nullptr, Hhi, nullptr, nullptr, 512, 512);
    gemm_kernel<2,0,1,0><<<dim3(8,32), 512, 0, stream>>>(
        Hhi, nbrwhi, nbr_b, nullptr, Anhi, nullptr, nullptr, 512, 512);
    nbr_attn_kernel<<<2048, 64, 0, stream>>>(Hhi, Anhi, H2hi);
    gemm_kernel<2,0,0,1><<<dim3(16,32), 512, 0, stream>>>(
        H2hi, prwhi, proto_b, nullptr, nullptr, templ, St, 1024, 1024);
    beta_embs_kernel<<<dim3(32,10), 256, 0, stream>>>(St, H2hi, embs, minv);
    glob_g2_kernel<<<dim3(128,10), 64, 0, stream>>>(embs, glob_w1, glob_b1, glob_w2, gpart);
    final3_kernel<<<1, 256, 0, stream>>>(gpart, glob_b2, embs, St, minv, cls_w, cls_b, out);
}